// Round 6
// baseline (338.818 us; speedup 1.0000x reference)
//
#include <hip/hip_runtime.h>
#include <math.h>

#define NN 50000
#define NNP (NN + 1)          // +1 dummy zero row per slice
#define NE 800000
#define NEP 1150000           // NE + 7*NN upper bound on padded edge count
#define NBLK 49               // ceil(NN/1024)
#define NBKT 7                // dst-range buckets (d >> 13)
#define BCAP 262144           // per-bucket bin capacity

typedef __attribute__((ext_vector_type(8))) short short8;
typedef __attribute__((ext_vector_type(4))) float float4v;

// bf16 helpers (RNE pack, shift unpack)
__device__ inline unsigned int f2bf(float f) {
  unsigned int u = __float_as_uint(f);
  return (u + 0x7fffu + ((u >> 16) & 1u)) >> 16;
}
__device__ inline unsigned int pack2bf(float lo, float hi) {
  return f2bf(lo) | (f2bf(hi) << 16);
}
__device__ inline float bflo(unsigned int p) { return __uint_as_float(p << 16); }
__device__ inline float bfhi(unsigned int p) { return __uint_as_float(p & 0xffff0000u); }

// ---------------- init: zero deg8/gstat/binCnt, prefill csr, W->bf16^T prep ----------------

__global__ __launch_bounds__(256) void k_init(int* __restrict__ deg8, float* __restrict__ gstat,
                                              int* __restrict__ csr, int* __restrict__ binCnt,
                                              const float* __restrict__ W0, const float* __restrict__ W1,
                                              const float* __restrict__ W2,
                                              unsigned short* __restrict__ wt16) {
  int i = blockIdx.x * 256 + threadIdx.x;
  if (i < NEP) csr[i] = NN;
  if (i < 8 * NN) deg8[i] = 0;
  if (i < 4096) gstat[i] = 0.f;  // 2 layers x 8 reps x [sum128|sumsq128]
  if (i < NBKT) binCnt[i] = 0;
  if (i < 32768) {               // W0^T, W1^T bf16
    int w = i >> 14;
    int rem = i & 16383;
    int k = rem >> 7;
    int n = rem & 127;
    const float* W = w ? W1 : W0;
    wt16[w * 16384 + n * 128 + k] = (unsigned short)f2bf(W[k * 128 + n]);
  } else if (i < 36864) {        // W2^T bf16 (32x128)
    int idx = i - 32768;
    int n = idx >> 7;
    int k = idx & 127;
    wt16[32768 + n * 128 + k] = (unsigned short)f2bf(W2[k * 32 + n]);
  }
}

// ---------------- pass A: degree count + dst-range binning ----------------

__global__ __launch_bounds__(1024) void k_binA(const int* __restrict__ src, const int* __restrict__ dst,
                                               int* __restrict__ deg8, int* __restrict__ binCnt,
                                               int2* __restrict__ bin) {
  __shared__ int lcnt[NBKT], lbase[NBKT];
  int tid = threadIdx.x;
  if (tid < NBKT) lcnt[tid] = 0;
  __syncthreads();
  int e = blockIdx.x * 1024 + tid;
  bool act = e < NE;
  int d = 0, s = 0, b = 0, rank = 0;
  if (act) {
    d = dst[e]; s = src[e];
    b = d >> 13;                       // 0..6
    atomicAdd(&deg8[(e & 7) * NN + d], 1);
    rank = atomicAdd(&lcnt[b], 1);
  }
  __syncthreads();
  if (tid < NBKT && lcnt[tid] > 0) lbase[tid] = atomicAdd(&binCnt[tid], lcnt[tid]);
  __syncthreads();
  if (act) bin[(size_t)b * BCAP + lbase[b] + rank] = make_int2(d, s);
}

// scan PADDED total degrees; also emit true total degree
__global__ __launch_bounds__(1024) void k_scan1(const int* __restrict__ deg8, int* __restrict__ degtot,
                                                int* __restrict__ excl, int* __restrict__ blksum) {
  __shared__ int sm[1024];
  int t = threadIdx.x;
  int i = blockIdx.x * 1024 + t;
  int tot = 0;
  if (i < NN) {
    #pragma unroll
    for (int j = 0; j < 8; j++) tot += deg8[j * NN + i];
    degtot[i] = tot;
  }
  int v = (i < NN) ? ((tot + 7) & ~7) : 0;
  sm[t] = v;
  __syncthreads();
  for (int off = 1; off < 1024; off <<= 1) {
    int x = (t >= off) ? sm[t - off] : 0;
    __syncthreads();
    sm[t] += x;
    __syncthreads();
  }
  if (i < NN) excl[i] = sm[t] - v;
  if (t == 1023) blksum[blockIdx.x] = sm[t];
}

__global__ void k_scan2(const int* __restrict__ blksum, int* __restrict__ blkoff,
                        int* __restrict__ rowstart) {
  int t = threadIdx.x;  // 64 threads, one wave
  int orig = (t < NBLK) ? blksum[t] : 0;
  int v = orig;
  #pragma unroll
  for (int off = 1; off < 64; off <<= 1) {
    int u = __shfl_up(v, off);
    if (t >= off) v += u;
  }
  if (t < NBLK) blkoff[t] = v - orig;
  if (t == NBLK - 1) rowstart[NN] = v;  // padded edge total
}

// finalize rowstart; dis; preload cursor; zero bf16 hs pad rows + h2 pad row
__global__ __launch_bounds__(256) void k_scan3(int* __restrict__ excl, const int* __restrict__ blkoff,
                                               const int* __restrict__ degtot, int* __restrict__ cursor,
                                               float* __restrict__ dis,
                                               unsigned short* __restrict__ hs16, float* __restrict__ h2) {
  int i = blockIdx.x * 256 + threadIdx.x;
  if (i < NN) {
    int rs = excl[i] + blkoff[i >> 10];
    excl[i] = rs;
    cursor[i] = rs;
    dis[i] = rsqrtf((float)degtot[i] + 1.0f);
  }
  if (i < 64) {   // hs16 pad row: 2 slices x 64 bf16 = 2 x 32 uints
    int slice = i >> 5, c = i & 31;
    ((unsigned int*)(hs16 + (size_t)slice * ((size_t)NNP * 64) + (size_t)NN * 64))[c] = 0u;
  }
  if (i < 32) h2[(size_t)NN * 32 + i] = 0.f;
}

// ---------------- pass B: scatter within XCD-pinned bucket ----------------

__global__ __launch_bounds__(256) void k_fillB(const int2* __restrict__ bin, const int* __restrict__ binCnt,
                                               int* __restrict__ cursor, int* __restrict__ csr_src) {
  int b = blockIdx.x & 7;
  if (b >= NBKT) return;
  int q = blockIdx.x >> 3;             // 0..63
  int cnt = binCnt[b];
  const int2* __restrict__ B = bin + (size_t)b * BCAP;
  for (int i = q * 256 + threadIdx.x; i < cnt; i += 64 * 256) {
    int2 ds = B[i];
    int p = atomicAdd(&cursor[ds.x], 1);
    csr_src[p] = ds.y;
  }
}

// ---------------- MFMA bf16 GEMM 128->128: 64-row tiles, wave-linear global access ----------------

__global__ __launch_bounds__(256) void k_gemm128(const float* __restrict__ X,
                                                 const unsigned short* __restrict__ Wt,
                                                 const float* __restrict__ dis,
                                                 unsigned short* __restrict__ hs16, int M) {
  __shared__ char smem[52224];
  unsigned short* A  = (unsigned short*)smem;            // [64][136]
  unsigned short* Bt = (unsigned short*)(smem + 17408);  // [128][136]
  float* C = (float*)smem;                               // [64][132] (reuse after compute)
  const int tid = threadIdx.x;
  const int row0 = blockIdx.x * 64;

  // stage A: wave-linear float4 mapping (4 KB contiguous per wave instr)
  {
    int c4 = tid & 31;   // float4 col within row
    #pragma unroll
    for (int i = 0; i < 8; i++) {
      int r = (tid >> 5) + i * 8;
      int gr = row0 + r;
      float4 v = make_float4(0.f, 0.f, 0.f, 0.f);
      if (gr < M) v = *(const float4*)(X + (size_t)gr * 128 + c4 * 4);
      *(uint2*)(A + r * 136 + c4 * 4) = make_uint2(pack2bf(v.x, v.y), pack2bf(v.z, v.w));
    }
  }
  // stage Bt: thread t -> row t>>1, 64 bf16 at (t&1)*64 = 8 x uint4 (L2-resident weights)
  {
    int r = tid >> 1, h = (tid & 1) * 64;
    const uint4* src = (const uint4*)(Wt + r * 128 + h);
    uint4* dst = (uint4*)(Bt + r * 136 + h);
    #pragma unroll
    for (int i = 0; i < 8; i++) dst[i] = src[i];
  }
  __syncthreads();

  const int wv = tid >> 6;       // 0..3
  const int l = tid & 63;
  const int lm = l & 15;
  const int lq = l >> 4;

  float4v acc[8];
  #pragma unroll
  for (int j = 0; j < 8; j++) acc[j] = (float4v)(0.f);

  const unsigned short* Arow = A + (wv * 16 + lm) * 136 + lq * 8;
  #pragma unroll
  for (int ks = 0; ks < 4; ks++) {
    short8 af = *(const short8*)(Arow + ks * 32);
    #pragma unroll
    for (int j = 0; j < 8; j++) {
      short8 bf = *(const short8*)(Bt + (j * 16 + lm) * 136 + lq * 8 + ks * 32);
      acc[j] = __builtin_amdgcn_mfma_f32_16x16x32_bf16(af, bf, acc[j], 0, 0, 0);
    }
  }
  __syncthreads();   // done reading A/Bt; reuse as C

  #pragma unroll
  for (int j = 0; j < 8; j++) {
    int col = j * 16 + lm;
    int rbase = wv * 16 + lq * 4;
    #pragma unroll
    for (int r = 0; r < 4; r++) C[(rbase + r) * 132 + col] = acc[j][r];
  }
  __syncthreads();

  // pack-out: wave-linear uint4 mapping over [2 slices][64 rows][8 uint4]
  {
    #pragma unroll
    for (int i = 0; i < 4; i++) {
      int idx = tid + i * 256;
      int slice = idx >> 9;
      int r = (idx >> 3) & 63;
      int ch = idx & 7;
      int gr = row0 + r;
      if (gr < M) {
        float d = dis[gr];
        const float* cp = C + r * 132 + slice * 64 + ch * 8;
        uint4 u;
        u.x = pack2bf(cp[0] * d, cp[1] * d);
        u.y = pack2bf(cp[2] * d, cp[3] * d);
        u.z = pack2bf(cp[4] * d, cp[5] * d);
        u.w = pack2bf(cp[6] * d, cp[7] * d);
        *(uint4*)(hs16 + (size_t)slice * ((size_t)NNP * 64) + (size_t)gr * 64 + ch * 8) = u;
      }
    }
  }
}

// ---------------- MFMA GEMM 128->128 with fused BN/ReLU/residual input ----------------
// O is packed bf16 (128/row); Xin is fp32 (original x). Writes XA as bf16.

__global__ __launch_bounds__(256) void k_gemm128f(const unsigned short* __restrict__ O16,
                                                  const float* __restrict__ Xin,
                                                  unsigned short* __restrict__ XA16,
                                                  const float* __restrict__ bnab,
                                                  const unsigned short* __restrict__ Wt,
                                                  const float* __restrict__ dis,
                                                  unsigned short* __restrict__ hs16, int M) {
  __shared__ char smem[52224];
  unsigned short* A  = (unsigned short*)smem;            // [64][136]
  unsigned short* Bt = (unsigned short*)(smem + 17408);  // [128][136]
  float* C = (float*)smem;                               // [64][132] (reuse after compute)
  const int tid = threadIdx.x;
  const int row0 = blockIdx.x * 64;

  // stage A fused: thread t -> 8-feat chunk c=t&15, rows (t>>4)+i*16
  {
    int c = tid & 15;
    float4 alo = *(const float4*)(bnab + c * 8);
    float4 ahi = *(const float4*)(bnab + c * 8 + 4);
    float4 clo = *(const float4*)(bnab + 128 + c * 8);
    float4 chi = *(const float4*)(bnab + 128 + c * 8 + 4);
    #pragma unroll
    for (int i = 0; i < 4; i++) {
      int r = (tid >> 4) + i * 16;
      int gr = row0 + r;
      uint4 u = make_uint4(0u, 0u, 0u, 0u);
      if (gr < M) {
        uint4 ou = *(const uint4*)(O16 + (size_t)gr * 128 + c * 8);
        float4 xlo = *(const float4*)(Xin + (size_t)gr * 128 + c * 8);
        float4 xhi = *(const float4*)(Xin + (size_t)gr * 128 + c * 8 + 4);
        float v0 = fmaxf(bflo(ou.x) * alo.x + clo.x, 0.f) + xlo.x;
        float v1 = fmaxf(bfhi(ou.x) * alo.y + clo.y, 0.f) + xlo.y;
        float v2 = fmaxf(bflo(ou.y) * alo.z + clo.z, 0.f) + xlo.z;
        float v3 = fmaxf(bfhi(ou.y) * alo.w + clo.w, 0.f) + xlo.w;
        float v4 = fmaxf(bflo(ou.z) * ahi.x + chi.x, 0.f) + xhi.x;
        float v5 = fmaxf(bfhi(ou.z) * ahi.y + chi.y, 0.f) + xhi.y;
        float v6 = fmaxf(bflo(ou.w) * ahi.z + chi.z, 0.f) + xhi.z;
        float v7 = fmaxf(bfhi(ou.w) * ahi.w + chi.w, 0.f) + xhi.w;
        u.x = pack2bf(v0, v1);
        u.y = pack2bf(v2, v3);
        u.z = pack2bf(v4, v5);
        u.w = pack2bf(v6, v7);
        *(uint4*)(XA16 + (size_t)gr * 128 + c * 8) = u;
      }
      *(uint4*)(A + r * 136 + c * 8) = u;
    }
  }
  // stage Bt
  {
    int r = tid >> 1, h = (tid & 1) * 64;
    const uint4* src = (const uint4*)(Wt + r * 128 + h);
    uint4* dst = (uint4*)(Bt + r * 136 + h);
    #pragma unroll
    for (int i = 0; i < 8; i++) dst[i] = src[i];
  }
  __syncthreads();

  const int wv = tid >> 6;
  const int l = tid & 63;
  const int lm = l & 15;
  const int lq = l >> 4;

  float4v acc[8];
  #pragma unroll
  for (int j = 0; j < 8; j++) acc[j] = (float4v)(0.f);

  const unsigned short* Arow = A + (wv * 16 + lm) * 136 + lq * 8;
  #pragma unroll
  for (int ks = 0; ks < 4; ks++) {
    short8 af = *(const short8*)(Arow + ks * 32);
    #pragma unroll
    for (int j = 0; j < 8; j++) {
      short8 bf = *(const short8*)(Bt + (j * 16 + lm) * 136 + lq * 8 + ks * 32);
      acc[j] = __builtin_amdgcn_mfma_f32_16x16x32_bf16(af, bf, acc[j], 0, 0, 0);
    }
  }
  __syncthreads();

  #pragma unroll
  for (int j = 0; j < 8; j++) {
    int col = j * 16 + lm;
    int rbase = wv * 16 + lq * 4;
    #pragma unroll
    for (int r = 0; r < 4; r++) C[(rbase + r) * 132 + col] = acc[j][r];
  }
  __syncthreads();

  // pack-out: wave-linear
  {
    #pragma unroll
    for (int i = 0; i < 4; i++) {
      int idx = tid + i * 256;
      int slice = idx >> 9;
      int r = (idx >> 3) & 63;
      int ch = idx & 7;
      int gr = row0 + r;
      if (gr < M) {
        float d = dis[gr];
        const float* cp = C + r * 132 + slice * 64 + ch * 8;
        uint4 u;
        u.x = pack2bf(cp[0] * d, cp[1] * d);
        u.y = pack2bf(cp[2] * d, cp[3] * d);
        u.z = pack2bf(cp[4] * d, cp[5] * d);
        u.w = pack2bf(cp[6] * d, cp[7] * d);
        *(uint4*)(hs16 + (size_t)slice * ((size_t)NNP * 64) + (size_t)gr * 64 + ch * 8) = u;
      }
    }
  }
}

// ---------------- MFMA bf16 GEMM 128->32 with fused BN/ReLU/residual input ----------------
// O and Xin both packed bf16. Final-layer input xb never materialized.

__global__ __launch_bounds__(256) void k_gemm32mf(const unsigned short* __restrict__ O16,
                                                  const unsigned short* __restrict__ XA16,
                                                  const float* __restrict__ bnab,
                                                  const unsigned short* __restrict__ Wt2,
                                                  const float* __restrict__ dis,
                                                  float* __restrict__ H, int M) {
  __shared__ char smem[26112];
  unsigned short* A   = (unsigned short*)smem;            // [64][136]
  unsigned short* Bt2 = (unsigned short*)(smem + 17408);  // [32][136]
  float* C = (float*)smem;                                // [64][36] (reuse)
  const int tid = threadIdx.x;
  const int row0 = blockIdx.x * 64;

  // stage A fused: bf16 O + bf16 residual
  {
    int c = tid & 15;
    float4 alo = *(const float4*)(bnab + c * 8);
    float4 ahi = *(const float4*)(bnab + c * 8 + 4);
    float4 clo = *(const float4*)(bnab + 128 + c * 8);
    float4 chi = *(const float4*)(bnab + 128 + c * 8 + 4);
    #pragma unroll
    for (int i = 0; i < 4; i++) {
      int r = (tid >> 4) + i * 16;
      int gr = row0 + r;
      uint4 u = make_uint4(0u, 0u, 0u, 0u);
      if (gr < M) {
        uint4 ou = *(const uint4*)(O16 + (size_t)gr * 128 + c * 8);
        uint4 xu = *(const uint4*)(XA16 + (size_t)gr * 128 + c * 8);
        float v0 = fmaxf(bflo(ou.x) * alo.x + clo.x, 0.f) + bflo(xu.x);
        float v1 = fmaxf(bfhi(ou.x) * alo.y + clo.y, 0.f) + bfhi(xu.x);
        float v2 = fmaxf(bflo(ou.y) * alo.z + clo.z, 0.f) + bflo(xu.y);
        float v3 = fmaxf(bfhi(ou.y) * alo.w + clo.w, 0.f) + bfhi(xu.y);
        float v4 = fmaxf(bflo(ou.z) * ahi.x + chi.x, 0.f) + bflo(xu.z);
        float v5 = fmaxf(bfhi(ou.z) * ahi.y + chi.y, 0.f) + bfhi(xu.z);
        float v6 = fmaxf(bflo(ou.w) * ahi.z + chi.z, 0.f) + bflo(xu.w);
        float v7 = fmaxf(bfhi(ou.w) * ahi.w + chi.w, 0.f) + bfhi(xu.w);
        u.x = pack2bf(v0, v1);
        u.y = pack2bf(v2, v3);
        u.z = pack2bf(v4, v5);
        u.w = pack2bf(v6, v7);
      }
      *(uint4*)(A + r * 136 + c * 8) = u;
    }
  }
  // stage Bt2: thread t -> row t>>3 (0..31), 16 bf16 at (t&7)*16 = 2 x uint4
  {
    int r = tid >> 3, h = (tid & 7) * 16;
    const uint4* src = (const uint4*)(Wt2 + r * 128 + h);
    uint4* dst = (uint4*)(Bt2 + r * 136 + h);
    dst[0] = src[0];
    dst[1] = src[1];
  }
  __syncthreads();

  const int wv = tid >> 6;
  const int l = tid & 63;
  const int lm = l & 15;
  const int lq = l >> 4;

  float4v acc[2];
  acc[0] = (float4v)(0.f);
  acc[1] = (float4v)(0.f);

  const unsigned short* Arow = A + (wv * 16 + lm) * 136 + lq * 8;
  #pragma unroll
  for (int ks = 0; ks < 4; ks++) {
    short8 af = *(const short8*)(Arow + ks * 32);
    #pragma unroll
    for (int j = 0; j < 2; j++) {
      short8 bf = *(const short8*)(Bt2 + (j * 16 + lm) * 136 + lq * 8 + ks * 32);
      acc[j] = __builtin_amdgcn_mfma_f32_16x16x32_bf16(af, bf, acc[j], 0, 0, 0);
    }
  }
  __syncthreads();   // reuse smem as C

  #pragma unroll
  for (int j = 0; j < 2; j++) {
    int col = j * 16 + lm;
    int rbase = wv * 16 + lq * 4;
    #pragma unroll
    for (int r = 0; r < 4; r++) C[(rbase + r) * 36 + col] = acc[j][r];
  }
  __syncthreads();

  // pack-out: wave-linear float4 over [64 rows][8 float4]
  {
    #pragma unroll
    for (int i = 0; i < 2; i++) {
      int idx = tid + i * 256;
      int r = idx >> 3;
      int ch = idx & 7;
      int gr = row0 + r;
      if (gr < M) {
        float d = dis[gr];
        const float* cp = C + r * 36 + ch * 4;
        float4 v = make_float4(cp[0] * d, cp[1] * d, cp[2] * d, cp[3] * d);
        *(float4*)(H + (size_t)gr * 32 + ch * 4) = v;
      }
    }
  }
}

// ---------------- aggregation layer 0/1: both slices per wave, 8 nodes/wave ----------------
// 2x-unrolled edge loop: two independent 8-edge groups per iteration -> 32 gathers
// in flight per wave (latency-bound kernel). Odd-group tail redirects group-B
// indices to the zeroed pad row NN (branch-free). Output packed bf16.
// Fused BN stats (fp32 registers) via LDS + 8-way replicated atomics.

__global__ __launch_bounds__(256) void k_agg128s(const unsigned short* __restrict__ Hs,
                                                 const float* __restrict__ dis,
                                                 const int* __restrict__ rowstart,
                                                 const int* __restrict__ csr_src,
                                                 const float* __restrict__ bias,
                                                 unsigned short* __restrict__ out16,
                                                 float* __restrict__ gstat) {
  __shared__ float smS[4][128], smQ[4][128];
  const int tid = threadIdx.x;
  const int wv = tid >> 6;
  const int lane = tid & 63;
  const int node_sub = lane >> 3;   // 0..7
  const int fl = lane & 7;          // 0..7 (8 bf16 = 16 B each)
  const int base = node_sub * 8;
  const int w = blockIdx.x * 32 + wv * 8 + node_sub;
  const bool act = w < NN;
  const unsigned short* __restrict__ S0 = Hs + fl * 8;
  const unsigned short* __restrict__ S1 = Hs + (size_t)NNP * 64 + fl * 8;
  float di = act ? dis[w] : 0.f;
  int e0 = 0, e1 = 0;
  if (act) { e0 = rowstart[w]; e1 = rowstart[w + 1]; }   // padded x8, group-uniform

  float a0[8], a1[8];
  #pragma unroll
  for (int j = 0; j < 8; j++) { a0[j] = 0.f; a1[j] = 0.f; }

  int idxA = (e0 < e1) ? csr_src[e0 + fl] : 0;
  int idxB = (e0 + 8 < e1) ? csr_src[e0 + 8 + fl] : 0;
  for (int e = e0; e < e1; e += 16) {
    int curA = idxA;
    int curB = (e + 8 < e1) ? idxB : (int)NN;   // NN -> zero pad row
    if (e + 16 < e1) idxA = csr_src[e + 16 + fl];
    if (e + 24 < e1) idxB = csr_src[e + 24 + fl];
    int sA0 = __shfl(curA, base + 0), sA1 = __shfl(curA, base + 1);
    int sA2 = __shfl(curA, base + 2), sA3 = __shfl(curA, base + 3);
    int sA4 = __shfl(curA, base + 4), sA5 = __shfl(curA, base + 5);
    int sA6 = __shfl(curA, base + 6), sA7 = __shfl(curA, base + 7);
    int sB0 = __shfl(curB, base + 0), sB1 = __shfl(curB, base + 1);
    int sB2 = __shfl(curB, base + 2), sB3 = __shfl(curB, base + 3);
    int sB4 = __shfl(curB, base + 4), sB5 = __shfl(curB, base + 5);
    int sB6 = __shfl(curB, base + 6), sB7 = __shfl(curB, base + 7);
    uint4 gA0 = *(const uint4*)(S0 + (size_t)sA0 * 64);
    uint4 gA1 = *(const uint4*)(S0 + (size_t)sA1 * 64);
    uint4 gA2 = *(const uint4*)(S0 + (size_t)sA2 * 64);
    uint4 gA3 = *(const uint4*)(S0 + (size_t)sA3 * 64);
    uint4 gA4 = *(const uint4*)(S0 + (size_t)sA4 * 64);
    uint4 gA5 = *(const uint4*)(S0 + (size_t)sA5 * 64);
    uint4 gA6 = *(const uint4*)(S0 + (size_t)sA6 * 64);
    uint4 gA7 = *(const uint4*)(S0 + (size_t)sA7 * 64);
    uint4 hA0 = *(const uint4*)(S1 + (size_t)sA0 * 64);
    uint4 hA1 = *(const uint4*)(S1 + (size_t)sA1 * 64);
    uint4 hA2 = *(const uint4*)(S1 + (size_t)sA2 * 64);
    uint4 hA3 = *(const uint4*)(S1 + (size_t)sA3 * 64);
    uint4 hA4 = *(const uint4*)(S1 + (size_t)sA4 * 64);
    uint4 hA5 = *(const uint4*)(S1 + (size_t)sA5 * 64);
    uint4 hA6 = *(const uint4*)(S1 + (size_t)sA6 * 64);
    uint4 hA7 = *(const uint4*)(S1 + (size_t)sA7 * 64);
    uint4 gB0 = *(const uint4*)(S0 + (size_t)sB0 * 64);
    uint4 gB1 = *(const uint4*)(S0 + (size_t)sB1 * 64);
    uint4 gB2 = *(const uint4*)(S0 + (size_t)sB2 * 64);
    uint4 gB3 = *(const uint4*)(S0 + (size_t)sB3 * 64);
    uint4 gB4 = *(const uint4*)(S0 + (size_t)sB4 * 64);
    uint4 gB5 = *(const uint4*)(S0 + (size_t)sB5 * 64);
    uint4 gB6 = *(const uint4*)(S0 + (size_t)sB6 * 64);
    uint4 gB7 = *(const uint4*)(S0 + (size_t)sB7 * 64);
    uint4 hB0 = *(const uint4*)(S1 + (size_t)sB0 * 64);
    uint4 hB1 = *(const uint4*)(S1 + (size_t)sB1 * 64);
    uint4 hB2 = *(const uint4*)(S1 + (size_t)sB2 * 64);
    uint4 hB3 = *(const uint4*)(S1 + (size_t)sB3 * 64);
    uint4 hB4 = *(const uint4*)(S1 + (size_t)sB4 * 64);
    uint4 hB5 = *(const uint4*)(S1 + (size_t)sB5 * 64);
    uint4 hB6 = *(const uint4*)(S1 + (size_t)sB6 * 64);
    uint4 hB7 = *(const uint4*)(S1 + (size_t)sB7 * 64);
    a0[0] += (((bflo(gA0.x) + bflo(gA1.x)) + (bflo(gA2.x) + bflo(gA3.x))) + ((bflo(gA4.x) + bflo(gA5.x)) + (bflo(gA6.x) + bflo(gA7.x))))
           + (((bflo(gB0.x) + bflo(gB1.x)) + (bflo(gB2.x) + bflo(gB3.x))) + ((bflo(gB4.x) + bflo(gB5.x)) + (bflo(gB6.x) + bflo(gB7.x))));
    a0[1] += (((bfhi(gA0.x) + bfhi(gA1.x)) + (bfhi(gA2.x) + bfhi(gA3.x))) + ((bfhi(gA4.x) + bfhi(gA5.x)) + (bfhi(gA6.x) + bfhi(gA7.x))))
           + (((bfhi(gB0.x) + bfhi(gB1.x)) + (bfhi(gB2.x) + bfhi(gB3.x))) + ((bfhi(gB4.x) + bfhi(gB5.x)) + (bfhi(gB6.x) + bfhi(gB7.x))));
    a0[2] += (((bflo(gA0.y) + bflo(gA1.y)) + (bflo(gA2.y) + bflo(gA3.y))) + ((bflo(gA4.y) + bflo(gA5.y)) + (bflo(gA6.y) + bflo(gA7.y))))
           + (((bflo(gB0.y) + bflo(gB1.y)) + (bflo(gB2.y) + bflo(gB3.y))) + ((bflo(gB4.y) + bflo(gB5.y)) + (bflo(gB6.y) + bflo(gB7.y))));
    a0[3] += (((bfhi(gA0.y) + bfhi(gA1.y)) + (bfhi(gA2.y) + bfhi(gA3.y))) + ((bfhi(gA4.y) + bfhi(gA5.y)) + (bfhi(gA6.y) + bfhi(gA7.y))))
           + (((bfhi(gB0.y) + bfhi(gB1.y)) + (bfhi(gB2.y) + bfhi(gB3.y))) + ((bfhi(gB4.y) + bfhi(gB5.y)) + (bfhi(gB6.y) + bfhi(gB7.y))));
    a0[4] += (((bflo(gA0.z) + bflo(gA1.z)) + (bflo(gA2.z) + bflo(gA3.z))) + ((bflo(gA4.z) + bflo(gA5.z)) + (bflo(gA6.z) + bflo(gA7.z))))
           + (((bflo(gB0.z) + bflo(gB1.z)) + (bflo(gB2.z) + bflo(gB3.z))) + ((bflo(gB4.z) + bflo(gB5.z)) + (bflo(gB6.z) + bflo(gB7.z))));
    a0[5] += (((bfhi(gA0.z) + bfhi(gA1.z)) + (bfhi(gA2.z) + bfhi(gA3.z))) + ((bfhi(gA4.z) + bfhi(gA5.z)) + (bfhi(gA6.z) + bfhi(gA7.z))))
           + (((bfhi(gB0.z) + bfhi(gB1.z)) + (bfhi(gB2.z) + bfhi(gB3.z))) + ((bfhi(gB4.z) + bfhi(gB5.z)) + (bfhi(gB6.z) + bfhi(gB7.z))));
    a0[6] += (((bflo(gA0.w) + bflo(gA1.w)) + (bflo(gA2.w) + bflo(gA3.w))) + ((bflo(gA4.w) + bflo(gA5.w)) + (bflo(gA6.w) + bflo(gA7.w))))
           + (((bflo(gB0.w) + bflo(gB1.w)) + (bflo(gB2.w) + bflo(gB3.w))) + ((bflo(gB4.w) + bflo(gB5.w)) + (bflo(gB6.w) + bflo(gB7.w))));
    a0[7] += (((bfhi(gA0.w) + bfhi(gA1.w)) + (bfhi(gA2.w) + bfhi(gA3.w))) + ((bfhi(gA4.w) + bfhi(gA5.w)) + (bfhi(gA6.w) + bfhi(gA7.w))))
           + (((bfhi(gB0.w) + bfhi(gB1.w)) + (bfhi(gB2.w) + bfhi(gB3.w))) + ((bfhi(gB4.w) + bfhi(gB5.w)) + (bfhi(gB6.w) + bfhi(gB7.w))));
    a1[0] += (((bflo(hA0.x) + bflo(hA1.x)) + (bflo(hA2.x) + bflo(hA3.x))) + ((bflo(hA4.x) + bflo(hA5.x)) + (bflo(hA6.x) + bflo(hA7.x))))
           + (((bflo(hB0.x) + bflo(hB1.x)) + (bflo(hB2.x) + bflo(hB3.x))) + ((bflo(hB4.x) + bflo(hB5.x)) + (bflo(hB6.x) + bflo(hB7.x))));
    a1[1] += (((bfhi(hA0.x) + bfhi(hA1.x)) + (bfhi(hA2.x) + bfhi(hA3.x))) + ((bfhi(hA4.x) + bfhi(hA5.x)) + (bfhi(hA6.x) + bfhi(hA7.x))))
           + (((bfhi(hB0.x) + bfhi(hB1.x)) + (bfhi(hB2.x) + bfhi(hB3.x))) + ((bfhi(hB4.x) + bfhi(hB5.x)) + (bfhi(hB6.x) + bfhi(hB7.x))));
    a1[2] += (((bflo(hA0.y) + bflo(hA1.y)) + (bflo(hA2.y) + bflo(hA3.y))) + ((bflo(hA4.y) + bflo(hA5.y)) + (bflo(hA6.y) + bflo(hA7.y))))
           + (((bflo(hB0.y) + bflo(hB1.y)) + (bflo(hB2.y) + bflo(hB3.y))) + ((bflo(hB4.y) + bflo(hB5.y)) + (bflo(hB6.y) + bflo(hB7.y))));
    a1[3] += (((bfhi(hA0.y) + bfhi(hA1.y)) + (bfhi(hA2.y) + bfhi(hA3.y))) + ((bfhi(hA4.y) + bfhi(hA5.y)) + (bfhi(hA6.y) + bfhi(hA7.y))))
           + (((bfhi(hB0.y) + bfhi(hB1.y)) + (bfhi(hB2.y) + bfhi(hB3.y))) + ((bfhi(hB4.y) + bfhi(hB5.y)) + (bfhi(hB6.y) + bfhi(hB7.y))));
    a1[4] += (((bflo(hA0.z) + bflo(hA1.z)) + (bflo(hA2.z) + bflo(hA3.z))) + ((bflo(hA4.z) + bflo(hA5.z)) + (bflo(hA6.z) + bflo(hA7.z))))
           + (((bflo(hB0.z) + bflo(hB1.z)) + (bflo(hB2.z) + bflo(hB3.z))) + ((bflo(hB4.z) + bflo(hB5.z)) + (bflo(hB6.z) + bflo(hB7.z))));
    a1[5] += (((bfhi(hA0.z) + bfhi(hA1.z)) + (bfhi(hA2.z) + bfhi(hA3.z))) + ((bfhi(hA4.z) + bfhi(hA5.z)) + (bfhi(hA6.z) + bfhi(hA7.z))))
           + (((bfhi(hB0.z) + bfhi(hB1.z)) + (bfhi(hB2.z) + bfhi(hB3.z))) + ((bfhi(hB4.z) + bfhi(hB5.z)) + (bfhi(hB6.z) + bfhi(hB7.z))));
    a1[6] += (((bflo(hA0.w) + bflo(hA1.w)) + (bflo(hA2.w) + bflo(hA3.w))) + ((bflo(hA4.w) + bflo(hA5.w)) + (bflo(hA6.w) + bflo(hA7.w))))
           + (((bflo(hB0.w) + bflo(hB1.w)) + (bflo(hB2.w) + bflo(hB3.w))) + ((bflo(hB4.w) + bflo(hB5.w)) + (bflo(hB6.w) + bflo(hB7.w))));
    a1[7] += (((bfhi(hA0.w) + bfhi(hA1.w)) + (bfhi(hA2.w) + bfhi(hA3.w))) + ((bfhi(hA4.w) + bfhi(hA5.w)) + (bfhi(hA6.w) + bfhi(hA7.w))))
           + (((bfhi(hB0.w) + bfhi(hB1.w)) + (bfhi(hB2.w) + bfhi(hB3.w))) + ((bfhi(hB4.w) + bfhi(hB5.w)) + (bfhi(hB6.w) + bfhi(hB7.w))));
  }

  float rv0[8], rv1[8];
  if (act) {
    uint4 sv0 = *(const uint4*)(S0 + (size_t)w * 64);
    uint4 sv1 = *(const uint4*)(S1 + (size_t)w * 64);
    float se0[8] = { bflo(sv0.x), bfhi(sv0.x), bflo(sv0.y), bfhi(sv0.y),
                     bflo(sv0.z), bfhi(sv0.z), bflo(sv0.w), bfhi(sv0.w) };
    float se1[8] = { bflo(sv1.x), bfhi(sv1.x), bflo(sv1.y), bfhi(sv1.y),
                     bflo(sv1.z), bfhi(sv1.z), bflo(sv1.w), bfhi(sv1.w) };
    #pragma unroll
    for (int j = 0; j < 8; j++) {
      rv0[j] = (a0[j] + se0[j]) * di + bias[fl * 8 + j];
      rv1[j] = (a1[j] + se1[j]) * di + bias[64 + fl * 8 + j];
    }
    uint4 u0, u1;
    u0.x = pack2bf(rv0[0], rv0[1]); u0.y = pack2bf(rv0[2], rv0[3]);
    u0.z = pack2bf(rv0[4], rv0[5]); u0.w = pack2bf(rv0[6], rv0[7]);
    u1.x = pack2bf(rv1[0], rv1[1]); u1.y = pack2bf(rv1[2], rv1[3]);
    u1.z = pack2bf(rv1[4], rv1[5]); u1.w = pack2bf(rv1[6], rv1[7]);
    *(uint4*)(out16 + (size_t)w * 128 + fl * 8)      = u0;
    *(uint4*)(out16 + (size_t)w * 128 + 64 + fl * 8) = u1;
  } else {
    #pragma unroll
    for (int j = 0; j < 8; j++) { rv0[j] = 0.f; rv1[j] = 0.f; }
  }

  // fused BN stats: reduce over node_sub (lane bits 3..5), then cross-wave via LDS
  float q0[8], q1[8];
  #pragma unroll
  for (int j = 0; j < 8; j++) { q0[j] = rv0[j] * rv0[j]; q1[j] = rv1[j] * rv1[j]; }
  #pragma unroll
  for (int off = 8; off <= 32; off <<= 1) {
    #pragma unroll
    for (int j = 0; j < 8; j++) {
      rv0[j] += __shfl_xor(rv0[j], off);
      q0[j]  += __shfl_xor(q0[j], off);
      rv1[j] += __shfl_xor(rv1[j], off);
      q1[j]  += __shfl_xor(q1[j], off);
    }
  }
  if (node_sub == 0) {
    #pragma unroll
    for (int j = 0; j < 8; j++) {
      smS[wv][fl * 8 + j] = rv0[j];      smQ[wv][fl * 8 + j] = q0[j];
      smS[wv][64 + fl * 8 + j] = rv1[j]; smQ[wv][64 + fl * 8 + j] = q1[j];
    }
  }
  __syncthreads();
  if (tid < 128) {
    float s = (smS[0][tid] + smS[1][tid]) + (smS[2][tid] + smS[3][tid]);
    float q = (smQ[0][tid] + smQ[1][tid]) + (smQ[2][tid] + smQ[3][tid]);
    int rep = blockIdx.x & 7;
    atomicAdd(&gstat[rep * 256 + tid], s);
    atomicAdd(&gstat[rep * 256 + 128 + tid], q);
  }
}

// ---------------- final layer: aggregation + fused log_softmax (fp32) ----------------
// 2x-unrolled edge loop (16 edges / 16 scalar gathers in flight per lane).

__global__ __launch_bounds__(256) void k_agg32lsm(const float* __restrict__ H2,
                                                  const float* __restrict__ dis,
                                                  const int* __restrict__ rowstart,
                                                  const int* __restrict__ csr_src,
                                                  const float* __restrict__ bias,
                                                  float* __restrict__ out) {
  int wave = (blockIdx.x * 256 + threadIdx.x) >> 6;
  int lane = threadIdx.x & 63;
  int half = lane >> 5;
  int l = lane & 31;
  int hbase = half * 32;
  int w = wave * 2 + half;
  if (w >= NN) return;   // NN even: both halves exit together
  const float* __restrict__ S = H2 + l;
  float di = dis[w];
  int e0 = rowstart[w], e1 = rowstart[w + 1];
  float acc = 0.f;
  int idxA = (e0 < e1) ? csr_src[e0 + (l & 7)] : 0;
  int idxB = (e0 + 8 < e1) ? csr_src[e0 + 8 + (l & 7)] : 0;
  for (int e = e0; e < e1; e += 16) {
    int curA = idxA;
    int curB = (e + 8 < e1) ? idxB : (int)NN;   // NN -> zero pad row
    if (e + 16 < e1) idxA = csr_src[e + 16 + (l & 7)];
    if (e + 24 < e1) idxB = csr_src[e + 24 + (l & 7)];
    int sA0 = __shfl(curA, hbase + 0), sA1 = __shfl(curA, hbase + 1);
    int sA2 = __shfl(curA, hbase + 2), sA3 = __shfl(curA, hbase + 3);
    int sA4 = __shfl(curA, hbase + 4), sA5 = __shfl(curA, hbase + 5);
    int sA6 = __shfl(curA, hbase + 6), sA7 = __shfl(curA, hbase + 7);
    int sB0 = __shfl(curB, hbase + 0), sB1 = __shfl(curB, hbase + 1);
    int sB2 = __shfl(curB, hbase + 2), sB3 = __shfl(curB, hbase + 3);
    int sB4 = __shfl(curB, hbase + 4), sB5 = __shfl(curB, hbase + 5);
    int sB6 = __shfl(curB, hbase + 6), sB7 = __shfl(curB, hbase + 7);
    float hA0 = S[(size_t)sA0 * 32], hA1 = S[(size_t)sA1 * 32];
    float hA2 = S[(size_t)sA2 * 32], hA3 = S[(size_t)sA3 * 32];
    float hA4 = S[(size_t)sA4 * 32], hA5 = S[(size_t)sA5 * 32];
    float hA6 = S[(size_t)sA6 * 32], hA7 = S[(size_t)sA7 * 32];
    float hB0 = S[(size_t)sB0 * 32], hB1 = S[(size_t)sB1 * 32];
    float hB2 = S[(size_t)sB2 * 32], hB3 = S[(size_t)sB3 * 32];
    float hB4 = S[(size_t)sB4 * 32], hB5 = S[(size_t)sB5 * 32];
    float hB6 = S[(size_t)sB6 * 32], hB7 = S[(size_t)sB7 * 32];
    acc += (((hA0 + hA1) + (hA2 + hA3)) + ((hA4 + hA5) + (hA6 + hA7)))
         + (((hB0 + hB1) + (hB2 + hB3)) + ((hB4 + hB5) + (hB6 + hB7)));
  }
  float v = (acc + S[(size_t)w * 32]) * di + bias[l];
  float m = v;
  #pragma unroll
  for (int off = 16; off >= 1; off >>= 1) m = fmaxf(m, __shfl_xor(m, off));
  float ex = expf(v - m);
  float s = ex;
  #pragma unroll
  for (int off = 16; off >= 1; off >>= 1) s += __shfl_xor(s, off);
  out[(size_t)w * 32 + l] = v - m - logf(s);
}

// ---------------- BN stats finalize: sum 8 reps, fold -> per-feature (a, c) ----------------

__global__ void k_bnfin(const float* __restrict__ gstat, const float* __restrict__ g,
                        const float* __restrict__ be, float* __restrict__ bnab) {
  int f = threadIdx.x;   // 128 threads
  float s = 0.f, q = 0.f;
  #pragma unroll
  for (int r = 0; r < 8; r++) {
    s += gstat[r * 256 + f];
    q += gstat[r * 256 + 128 + f];
  }
  const float inv = 1.f / (float)NN;
  float m = s * inv;
  float var = q * inv - m * m;
  float a = rsqrtf(var + 1e-5f) * g[f];
  bnab[f] = a;
  bnab[128 + f] = be[f] - m * a;
}

// ---------------- launch ----------------

extern "C" void kernel_launch(void* const* d_in, const int* in_sizes, int n_in,
                              void* d_out, int out_size, void* d_ws, size_t ws_size,
                              hipStream_t stream) {
  const float* x   = (const float*)d_in[0];
  const int*   ei  = (const int*)d_in[1];
  const float* W0  = (const float*)d_in[2];
  const float* b0  = (const float*)d_in[3];
  const float* g0  = (const float*)d_in[4];
  const float* be0 = (const float*)d_in[5];
  const float* W1  = (const float*)d_in[6];
  const float* b1  = (const float*)d_in[7];
  const float* g1  = (const float*)d_in[8];
  const float* be1 = (const float*)d_in[9];
  const float* W2  = (const float*)d_in[10];
  const float* b2  = (const float*)d_in[11];
  float* out = (float*)d_out;
  const int* srcI = ei;
  const int* dstI = ei + NE;

  char* p = (char*)d_ws;
  auto take = [&](size_t bytes) { char* r = p; p += (bytes + 255) & ~(size_t)255; return (void*)r; };
  int*   deg8     = (int*)take((size_t)8 * NN * 4);
  int*   cursor   = (int*)take(NN * 4);
  int*   degtot   = (int*)take(NN * 4);
  int*   rowstart = (int*)take((NN + 1) * 4);
  int*   blksum   = (int*)take(64 * 4);
  int*   blkoff   = (int*)take(64 * 4);
  int*   binCnt   = (int*)take(8 * 4);
  float* dis      = (float*)take(NN * 4);
  int*   csr      = (int*)take((size_t)NEP * 4);
  int2*  bin      = (int2*)take((size_t)NBKT * BCAP * 8);
  float* gstat    = (float*)take(4096 * 4);  // 2 layers x 8 reps x 256
  float* bnab     = (float*)take(512 * 4);   // layer0: a[128],c[128]; layer1: +256
  unsigned short* wt16 = (unsigned short*)take((2 * 16384 + 4096) * 2);  // W0^T, W1^T, W2^T bf16
  unsigned short* hs16 = (unsigned short*)take((size_t)NNP * 128 * 2);   // bf16, 2-slice-major
  unsigned short* o16  = (unsigned short*)take((size_t)NN * 128 * 2);    // agg output, packed bf16
  unsigned short* xA16 = (unsigned short*)take((size_t)NN * 128 * 2);    // layer-1 input, packed bf16
  float* h2       = (float*)take((size_t)NNP * 32 * 4);

  k_init<<<(NEP + 255) / 256, 256, 0, stream>>>(deg8, gstat, csr, binCnt, W0, W1, W2, wt16);
  k_binA<<<(NE + 1023) / 1024, 1024, 0, stream>>>(srcI, dstI, deg8, binCnt, bin);
  k_scan1<<<NBLK, 1024, 0, stream>>>(deg8, degtot, rowstart, blksum);
  k_scan2<<<1, 64, 0, stream>>>(blksum, blkoff, rowstart);
  k_scan3<<<(NN + 255) / 256, 256, 0, stream>>>(rowstart, blkoff, degtot, cursor, dis, hs16, h2);
  k_fillB<<<512, 256, 0, stream>>>(bin, binCnt, cursor, csr);

  const int aggGrid = (NN + 31) / 32;   // 8 nodes/wave, both slices, 4 waves/block
  const int aggGrid32 = (NN + 7) / 8;   // 2 nodes/wave

  // ---- layer 0 ----
  k_gemm128<<<(NN + 63) / 64, 256, 0, stream>>>(x, wt16, dis, hs16, NN);
  k_agg128s<<<aggGrid, 256, 0, stream>>>(hs16, dis, rowstart, csr, b0, o16, gstat);
  k_bnfin<<<1, 128, 0, stream>>>(gstat, g0, be0, bnab);

  // ---- layer 1 (BN/ReLU/residual of layer 0 fused into GEMM stage-A) ----
  k_gemm128f<<<(NN + 63) / 64, 256, 0, stream>>>(o16, x, xA16, bnab, wt16 + 16384, dis, hs16, NN);
  k_agg128s<<<aggGrid, 256, 0, stream>>>(hs16, dis, rowstart, csr, b1, o16, gstat + 2048);
  k_bnfin<<<1, 128, 0, stream>>>(gstat + 2048, g1, be1, bnab + 256);

  // ---- final conv (BN/ReLU/residual of layer 1 fused, xB never materialized) ----
  k_gemm32mf<<<(NN + 63) / 64, 256, 0, stream>>>(o16, xA16, bnab + 256, wt16 + 32768, dis, h2, NN);
  k_agg32lsm<<<aggGrid32, 256, 0, stream>>>(h2, dis, rowstart, csr, b2, out);
}

// Round 7
// 289.995 us; speedup vs baseline: 1.1684x; 1.1684x over previous
//
#include <hip/hip_runtime.h>
#include <math.h>

#define NN 50000
#define NNP (NN + 1)          // +1 dummy zero row per slice
#define NE 800000
#define NEP 1150000           // NE + 7*NN upper bound on padded edge count
#define NBLK 49               // ceil(NN/1024)
#define NBKT 7                // dst-range buckets (d >> 13)
#define BCAP 262144           // per-bucket bin capacity

typedef __attribute__((ext_vector_type(8))) short short8;
typedef __attribute__((ext_vector_type(4))) float float4v;

// bf16 helpers (RNE pack, shift unpack)
__device__ inline unsigned int f2bf(float f) {
  unsigned int u = __float_as_uint(f);
  return (u + 0x7fffu + ((u >> 16) & 1u)) >> 16;
}
__device__ inline unsigned int pack2bf(float lo, float hi) {
  return f2bf(lo) | (f2bf(hi) << 16);
}
__device__ inline float bflo(unsigned int p) { return __uint_as_float(p << 16); }
__device__ inline float bfhi(unsigned int p) { return __uint_as_float(p & 0xffff0000u); }

// BN finalize fold, shared by the fused GEMMs: 8-replica gstat -> (a, c) in LDS.
__device__ inline void bn_fold(const float* __restrict__ gstat, const float* __restrict__ g,
                               const float* __restrict__ be, float* __restrict__ bnabS, int tid) {
  if (tid < 128) {
    float s = 0.f, q = 0.f;
    #pragma unroll
    for (int r = 0; r < 8; r++) {
      s += gstat[r * 256 + tid];
      q += gstat[r * 256 + 128 + tid];
    }
    const float inv = 1.f / (float)NN;
    float m = s * inv;
    float var = q * inv - m * m;
    float a = rsqrtf(var + 1e-5f) * g[tid];
    bnabS[tid] = a;
    bnabS[128 + tid] = be[tid] - m * a;
  }
}

// ---------------- init: zero deg8/gstat/binCnt, prefill csr, W->bf16^T prep ----------------

__global__ __launch_bounds__(256) void k_init(int* __restrict__ deg8, float* __restrict__ gstat,
                                              int* __restrict__ csr, int* __restrict__ binCnt,
                                              const float* __restrict__ W0, const float* __restrict__ W1,
                                              const float* __restrict__ W2,
                                              unsigned short* __restrict__ wt16) {
  int i = blockIdx.x * 256 + threadIdx.x;
  if (i < NEP) csr[i] = NN;
  if (i < 8 * NN) deg8[i] = 0;
  if (i < 4096) gstat[i] = 0.f;  // 2 layers x 8 reps x [sum128|sumsq128]
  if (i < NBKT) binCnt[i] = 0;
  if (i < 32768) {               // W0^T, W1^T bf16
    int w = i >> 14;
    int rem = i & 16383;
    int k = rem >> 7;
    int n = rem & 127;
    const float* W = w ? W1 : W0;
    wt16[w * 16384 + n * 128 + k] = (unsigned short)f2bf(W[k * 128 + n]);
  } else if (i < 36864) {        // W2^T bf16 (32x128)
    int idx = i - 32768;
    int n = idx >> 7;
    int k = idx & 127;
    wt16[32768 + n * 128 + k] = (unsigned short)f2bf(W2[k * 32 + n]);
  }
}

// ---------------- pass A: degree count + dst-range binning ----------------

__global__ __launch_bounds__(1024) void k_binA(const int* __restrict__ src, const int* __restrict__ dst,
                                               int* __restrict__ deg8, int* __restrict__ binCnt,
                                               int2* __restrict__ bin) {
  __shared__ int lcnt[NBKT], lbase[NBKT];
  int tid = threadIdx.x;
  if (tid < NBKT) lcnt[tid] = 0;
  __syncthreads();
  int e = blockIdx.x * 1024 + tid;
  bool act = e < NE;
  int d = 0, s = 0, b = 0, rank = 0;
  if (act) {
    d = dst[e]; s = src[e];
    b = d >> 13;                       // 0..6
    atomicAdd(&deg8[(e & 7) * NN + d], 1);
    rank = atomicAdd(&lcnt[b], 1);
  }
  __syncthreads();
  if (tid < NBKT && lcnt[tid] > 0) lbase[tid] = atomicAdd(&binCnt[tid], lcnt[tid]);
  __syncthreads();
  if (act) bin[(size_t)b * BCAP + lbase[b] + rank] = make_int2(d, s);
}

// scan PADDED total degrees; also emit true total degree
__global__ __launch_bounds__(1024) void k_scan1(const int* __restrict__ deg8, int* __restrict__ degtot,
                                                int* __restrict__ excl, int* __restrict__ blksum) {
  __shared__ int sm[1024];
  int t = threadIdx.x;
  int i = blockIdx.x * 1024 + t;
  int tot = 0;
  if (i < NN) {
    #pragma unroll
    for (int j = 0; j < 8; j++) tot += deg8[j * NN + i];
    degtot[i] = tot;
  }
  int v = (i < NN) ? ((tot + 7) & ~7) : 0;
  sm[t] = v;
  __syncthreads();
  for (int off = 1; off < 1024; off <<= 1) {
    int x = (t >= off) ? sm[t - off] : 0;
    __syncthreads();
    sm[t] += x;
    __syncthreads();
  }
  if (i < NN) excl[i] = sm[t] - v;
  if (t == 1023) blksum[blockIdx.x] = sm[t];
}

__global__ void k_scan2(const int* __restrict__ blksum, int* __restrict__ blkoff,
                        int* __restrict__ rowstart) {
  int t = threadIdx.x;  // 64 threads, one wave
  int orig = (t < NBLK) ? blksum[t] : 0;
  int v = orig;
  #pragma unroll
  for (int off = 1; off < 64; off <<= 1) {
    int u = __shfl_up(v, off);
    if (t >= off) v += u;
  }
  if (t < NBLK) blkoff[t] = v - orig;
  if (t == NBLK - 1) rowstart[NN] = v;  // padded edge total
}

// finalize rowstart; dis; preload cursor; zero bf16 hs pad rows + h2 pad row
__global__ __launch_bounds__(256) void k_scan3(int* __restrict__ excl, const int* __restrict__ blkoff,
                                               const int* __restrict__ degtot, int* __restrict__ cursor,
                                               float* __restrict__ dis,
                                               unsigned short* __restrict__ hs16, float* __restrict__ h2) {
  int i = blockIdx.x * 256 + threadIdx.x;
  if (i < NN) {
    int rs = excl[i] + blkoff[i >> 10];
    excl[i] = rs;
    cursor[i] = rs;
    dis[i] = rsqrtf((float)degtot[i] + 1.0f);
  }
  if (i < 64) {   // hs16 pad row: 2 slices x 64 bf16 = 2 x 32 uints
    int slice = i >> 5, c = i & 31;
    ((unsigned int*)(hs16 + (size_t)slice * ((size_t)NNP * 64) + (size_t)NN * 64))[c] = 0u;
  }
  if (i < 32) h2[(size_t)NN * 32 + i] = 0.f;
}

// ---------------- pass B: scatter within XCD-pinned bucket ----------------

__global__ __launch_bounds__(256) void k_fillB(const int2* __restrict__ bin, const int* __restrict__ binCnt,
                                               int* __restrict__ cursor, int* __restrict__ csr_src) {
  int b = blockIdx.x & 7;
  if (b >= NBKT) return;
  int q = blockIdx.x >> 3;             // 0..63
  int cnt = binCnt[b];
  const int2* __restrict__ B = bin + (size_t)b * BCAP;
  for (int i = q * 256 + threadIdx.x; i < cnt; i += 64 * 256) {
    int2 ds = B[i];
    int p = atomicAdd(&cursor[ds.x], 1);
    csr_src[p] = ds.y;
  }
}

// ---------------- MFMA bf16 GEMM 128->128: 64-row tiles, wave-linear global access ----------------

__global__ __launch_bounds__(256) void k_gemm128(const float* __restrict__ X,
                                                 const unsigned short* __restrict__ Wt,
                                                 const float* __restrict__ dis,
                                                 unsigned short* __restrict__ hs16, int M) {
  __shared__ char smem[52224];
  unsigned short* A  = (unsigned short*)smem;            // [64][136]
  unsigned short* Bt = (unsigned short*)(smem + 17408);  // [128][136]
  float* C = (float*)smem;                               // [64][132] (reuse after compute)
  const int tid = threadIdx.x;
  const int row0 = blockIdx.x * 64;

  // stage A: wave-linear float4 mapping (4 KB contiguous per wave instr)
  {
    int c4 = tid & 31;   // float4 col within row
    #pragma unroll
    for (int i = 0; i < 8; i++) {
      int r = (tid >> 5) + i * 8;
      int gr = row0 + r;
      float4 v = make_float4(0.f, 0.f, 0.f, 0.f);
      if (gr < M) v = *(const float4*)(X + (size_t)gr * 128 + c4 * 4);
      *(uint2*)(A + r * 136 + c4 * 4) = make_uint2(pack2bf(v.x, v.y), pack2bf(v.z, v.w));
    }
  }
  // stage Bt: thread t -> row t>>1, 64 bf16 at (t&1)*64 = 8 x uint4 (L2-resident weights)
  {
    int r = tid >> 1, h = (tid & 1) * 64;
    const uint4* src = (const uint4*)(Wt + r * 128 + h);
    uint4* dst = (uint4*)(Bt + r * 136 + h);
    #pragma unroll
    for (int i = 0; i < 8; i++) dst[i] = src[i];
  }
  __syncthreads();

  const int wv = tid >> 6;       // 0..3
  const int l = tid & 63;
  const int lm = l & 15;
  const int lq = l >> 4;

  float4v acc[8];
  #pragma unroll
  for (int j = 0; j < 8; j++) acc[j] = (float4v)(0.f);

  const unsigned short* Arow = A + (wv * 16 + lm) * 136 + lq * 8;
  #pragma unroll
  for (int ks = 0; ks < 4; ks++) {
    short8 af = *(const short8*)(Arow + ks * 32);
    #pragma unroll
    for (int j = 0; j < 8; j++) {
      short8 bf = *(const short8*)(Bt + (j * 16 + lm) * 136 + lq * 8 + ks * 32);
      acc[j] = __builtin_amdgcn_mfma_f32_16x16x32_bf16(af, bf, acc[j], 0, 0, 0);
    }
  }
  __syncthreads();   // done reading A/Bt; reuse as C

  #pragma unroll
  for (int j = 0; j < 8; j++) {
    int col = j * 16 + lm;
    int rbase = wv * 16 + lq * 4;
    #pragma unroll
    for (int r = 0; r < 4; r++) C[(rbase + r) * 132 + col] = acc[j][r];
  }
  __syncthreads();

  // pack-out: wave-linear uint4 mapping over [2 slices][64 rows][8 uint4]
  {
    #pragma unroll
    for (int i = 0; i < 4; i++) {
      int idx = tid + i * 256;
      int slice = idx >> 9;
      int r = (idx >> 3) & 63;
      int ch = idx & 7;
      int gr = row0 + r;
      if (gr < M) {
        float d = dis[gr];
        const float* cp = C + r * 132 + slice * 64 + ch * 8;
        uint4 u;
        u.x = pack2bf(cp[0] * d, cp[1] * d);
        u.y = pack2bf(cp[2] * d, cp[3] * d);
        u.z = pack2bf(cp[4] * d, cp[5] * d);
        u.w = pack2bf(cp[6] * d, cp[7] * d);
        *(uint4*)(hs16 + (size_t)slice * ((size_t)NNP * 64) + (size_t)gr * 64 + ch * 8) = u;
      }
    }
  }
}

// ---------------- MFMA GEMM 128->128 with fused BN(fold)/ReLU/residual input ----------------
// O is packed bf16 (128/row); Xin is fp32 (original x). Writes XA as bf16.
// BN finalize (gstat -> a,c) computed in-block into LDS (replaces k_bnfin launch).

__global__ __launch_bounds__(256) void k_gemm128f(const unsigned short* __restrict__ O16,
                                                  const float* __restrict__ Xin,
                                                  unsigned short* __restrict__ XA16,
                                                  const float* __restrict__ gstat,
                                                  const float* __restrict__ g,
                                                  const float* __restrict__ be,
                                                  const unsigned short* __restrict__ Wt,
                                                  const float* __restrict__ dis,
                                                  unsigned short* __restrict__ hs16, int M) {
  __shared__ char smem[52224];
  __shared__ float bnabS[256];
  unsigned short* A  = (unsigned short*)smem;            // [64][136]
  unsigned short* Bt = (unsigned short*)(smem + 17408);  // [128][136]
  float* C = (float*)smem;                               // [64][132] (reuse after compute)
  const int tid = threadIdx.x;
  const int row0 = blockIdx.x * 64;

  bn_fold(gstat, g, be, bnabS, tid);
  __syncthreads();

  // stage A fused: thread t -> 8-feat chunk c=t&15, rows (t>>4)+i*16
  {
    int c = tid & 15;
    float4 alo = *(const float4*)(bnabS + c * 8);
    float4 ahi = *(const float4*)(bnabS + c * 8 + 4);
    float4 clo = *(const float4*)(bnabS + 128 + c * 8);
    float4 chi = *(const float4*)(bnabS + 128 + c * 8 + 4);
    #pragma unroll
    for (int i = 0; i < 4; i++) {
      int r = (tid >> 4) + i * 16;
      int gr = row0 + r;
      uint4 u = make_uint4(0u, 0u, 0u, 0u);
      if (gr < M) {
        uint4 ou = *(const uint4*)(O16 + (size_t)gr * 128 + c * 8);
        float4 xlo = *(const float4*)(Xin + (size_t)gr * 128 + c * 8);
        float4 xhi = *(const float4*)(Xin + (size_t)gr * 128 + c * 8 + 4);
        float v0 = fmaxf(bflo(ou.x) * alo.x + clo.x, 0.f) + xlo.x;
        float v1 = fmaxf(bfhi(ou.x) * alo.y + clo.y, 0.f) + xlo.y;
        float v2 = fmaxf(bflo(ou.y) * alo.z + clo.z, 0.f) + xlo.z;
        float v3 = fmaxf(bfhi(ou.y) * alo.w + clo.w, 0.f) + xlo.w;
        float v4 = fmaxf(bflo(ou.z) * ahi.x + chi.x, 0.f) + xhi.x;
        float v5 = fmaxf(bfhi(ou.z) * ahi.y + chi.y, 0.f) + xhi.y;
        float v6 = fmaxf(bflo(ou.w) * ahi.z + chi.z, 0.f) + xhi.z;
        float v7 = fmaxf(bfhi(ou.w) * ahi.w + chi.w, 0.f) + xhi.w;
        u.x = pack2bf(v0, v1);
        u.y = pack2bf(v2, v3);
        u.z = pack2bf(v4, v5);
        u.w = pack2bf(v6, v7);
        *(uint4*)(XA16 + (size_t)gr * 128 + c * 8) = u;
      }
      *(uint4*)(A + r * 136 + c * 8) = u;
    }
  }
  // stage Bt
  {
    int r = tid >> 1, h = (tid & 1) * 64;
    const uint4* src = (const uint4*)(Wt + r * 128 + h);
    uint4* dst = (uint4*)(Bt + r * 136 + h);
    #pragma unroll
    for (int i = 0; i < 8; i++) dst[i] = src[i];
  }
  __syncthreads();

  const int wv = tid >> 6;
  const int l = tid & 63;
  const int lm = l & 15;
  const int lq = l >> 4;

  float4v acc[8];
  #pragma unroll
  for (int j = 0; j < 8; j++) acc[j] = (float4v)(0.f);

  const unsigned short* Arow = A + (wv * 16 + lm) * 136 + lq * 8;
  #pragma unroll
  for (int ks = 0; ks < 4; ks++) {
    short8 af = *(const short8*)(Arow + ks * 32);
    #pragma unroll
    for (int j = 0; j < 8; j++) {
      short8 bf = *(const short8*)(Bt + (j * 16 + lm) * 136 + lq * 8 + ks * 32);
      acc[j] = __builtin_amdgcn_mfma_f32_16x16x32_bf16(af, bf, acc[j], 0, 0, 0);
    }
  }
  __syncthreads();

  #pragma unroll
  for (int j = 0; j < 8; j++) {
    int col = j * 16 + lm;
    int rbase = wv * 16 + lq * 4;
    #pragma unroll
    for (int r = 0; r < 4; r++) C[(rbase + r) * 132 + col] = acc[j][r];
  }
  __syncthreads();

  // pack-out: wave-linear
  {
    #pragma unroll
    for (int i = 0; i < 4; i++) {
      int idx = tid + i * 256;
      int slice = idx >> 9;
      int r = (idx >> 3) & 63;
      int ch = idx & 7;
      int gr = row0 + r;
      if (gr < M) {
        float d = dis[gr];
        const float* cp = C + r * 132 + slice * 64 + ch * 8;
        uint4 u;
        u.x = pack2bf(cp[0] * d, cp[1] * d);
        u.y = pack2bf(cp[2] * d, cp[3] * d);
        u.z = pack2bf(cp[4] * d, cp[5] * d);
        u.w = pack2bf(cp[6] * d, cp[7] * d);
        *(uint4*)(hs16 + (size_t)slice * ((size_t)NNP * 64) + (size_t)gr * 64 + ch * 8) = u;
      }
    }
  }
}

// ---------------- MFMA bf16 GEMM 128->32 with fused BN(fold)/ReLU/residual input ----------------
// O and Xin both packed bf16. Final-layer input xb never materialized.

__global__ __launch_bounds__(256) void k_gemm32mf(const unsigned short* __restrict__ O16,
                                                  const unsigned short* __restrict__ XA16,
                                                  const float* __restrict__ gstat,
                                                  const float* __restrict__ g,
                                                  const float* __restrict__ be,
                                                  const unsigned short* __restrict__ Wt2,
                                                  const float* __restrict__ dis,
                                                  float* __restrict__ H, int M) {
  __shared__ char smem[26112];
  __shared__ float bnabS[256];
  unsigned short* A   = (unsigned short*)smem;            // [64][136]
  unsigned short* Bt2 = (unsigned short*)(smem + 17408);  // [32][136]
  float* C = (float*)smem;                                // [64][36] (reuse)
  const int tid = threadIdx.x;
  const int row0 = blockIdx.x * 64;

  bn_fold(gstat, g, be, bnabS, tid);
  __syncthreads();

  // stage A fused: bf16 O + bf16 residual
  {
    int c = tid & 15;
    float4 alo = *(const float4*)(bnabS + c * 8);
    float4 ahi = *(const float4*)(bnabS + c * 8 + 4);
    float4 clo = *(const float4*)(bnabS + 128 + c * 8);
    float4 chi = *(const float4*)(bnabS + 128 + c * 8 + 4);
    #pragma unroll
    for (int i = 0; i < 4; i++) {
      int r = (tid >> 4) + i * 16;
      int gr = row0 + r;
      uint4 u = make_uint4(0u, 0u, 0u, 0u);
      if (gr < M) {
        uint4 ou = *(const uint4*)(O16 + (size_t)gr * 128 + c * 8);
        uint4 xu = *(const uint4*)(XA16 + (size_t)gr * 128 + c * 8);
        float v0 = fmaxf(bflo(ou.x) * alo.x + clo.x, 0.f) + bflo(xu.x);
        float v1 = fmaxf(bfhi(ou.x) * alo.y + clo.y, 0.f) + bfhi(xu.x);
        float v2 = fmaxf(bflo(ou.y) * alo.z + clo.z, 0.f) + bflo(xu.y);
        float v3 = fmaxf(bfhi(ou.y) * alo.w + clo.w, 0.f) + bfhi(xu.y);
        float v4 = fmaxf(bflo(ou.z) * ahi.x + chi.x, 0.f) + bflo(xu.z);
        float v5 = fmaxf(bfhi(ou.z) * ahi.y + chi.y, 0.f) + bfhi(xu.z);
        float v6 = fmaxf(bflo(ou.w) * ahi.z + chi.z, 0.f) + bflo(xu.w);
        float v7 = fmaxf(bfhi(ou.w) * ahi.w + chi.w, 0.f) + bfhi(xu.w);
        u.x = pack2bf(v0, v1);
        u.y = pack2bf(v2, v3);
        u.z = pack2bf(v4, v5);
        u.w = pack2bf(v6, v7);
      }
      *(uint4*)(A + r * 136 + c * 8) = u;
    }
  }
  // stage Bt2: thread t -> row t>>3 (0..31), 16 bf16 at (t&7)*16 = 2 x uint4
  {
    int r = tid >> 3, h = (tid & 7) * 16;
    const uint4* src = (const uint4*)(Wt2 + r * 128 + h);
    uint4* dst = (uint4*)(Bt2 + r * 136 + h);
    dst[0] = src[0];
    dst[1] = src[1];
  }
  __syncthreads();

  const int wv = tid >> 6;
  const int l = tid & 63;
  const int lm = l & 15;
  const int lq = l >> 4;

  float4v acc[2];
  acc[0] = (float4v)(0.f);
  acc[1] = (float4v)(0.f);

  const unsigned short* Arow = A + (wv * 16 + lm) * 136 + lq * 8;
  #pragma unroll
  for (int ks = 0; ks < 4; ks++) {
    short8 af = *(const short8*)(Arow + ks * 32);
    #pragma unroll
    for (int j = 0; j < 2; j++) {
      short8 bf = *(const short8*)(Bt2 + (j * 16 + lm) * 136 + lq * 8 + ks * 32);
      acc[j] = __builtin_amdgcn_mfma_f32_16x16x32_bf16(af, bf, acc[j], 0, 0, 0);
    }
  }
  __syncthreads();   // reuse smem as C

  #pragma unroll
  for (int j = 0; j < 2; j++) {
    int col = j * 16 + lm;
    int rbase = wv * 16 + lq * 4;
    #pragma unroll
    for (int r = 0; r < 4; r++) C[(rbase + r) * 36 + col] = acc[j][r];
  }
  __syncthreads();

  // pack-out: wave-linear float4 over [64 rows][8 float4]
  {
    #pragma unroll
    for (int i = 0; i < 2; i++) {
      int idx = tid + i * 256;
      int r = idx >> 3;
      int ch = idx & 7;
      int gr = row0 + r;
      if (gr < M) {
        float d = dis[gr];
        const float* cp = C + r * 36 + ch * 4;
        float4 v = make_float4(cp[0] * d, cp[1] * d, cp[2] * d, cp[3] * d);
        *(float4*)(H + (size_t)gr * 32 + ch * 4) = v;
      }
    }
  }
}

// ---------------- aggregation layer 0/1: both slices per wave, 8 nodes/wave ----------------
// R5-proven shape: 16 gathers in flight per lane, csr prefetched one iteration
// ahead, 40-VGPR class (do NOT unroll 2x: R6 showed 132 VGPR -> occupancy collapse).
// Output packed bf16. Fused BN stats (fp32 registers) via LDS + 8-way replicated atomics.

__global__ __launch_bounds__(256) void k_agg128s(const unsigned short* __restrict__ Hs,
                                                 const float* __restrict__ dis,
                                                 const int* __restrict__ rowstart,
                                                 const int* __restrict__ csr_src,
                                                 const float* __restrict__ bias,
                                                 unsigned short* __restrict__ out16,
                                                 float* __restrict__ gstat) {
  __shared__ float smS[4][128], smQ[4][128];
  const int tid = threadIdx.x;
  const int wv = tid >> 6;
  const int lane = tid & 63;
  const int node_sub = lane >> 3;   // 0..7
  const int fl = lane & 7;          // 0..7 (8 bf16 = 16 B each)
  const int base = node_sub * 8;
  const int w = blockIdx.x * 32 + wv * 8 + node_sub;
  const bool act = w < NN;
  const unsigned short* __restrict__ S0 = Hs + fl * 8;
  const unsigned short* __restrict__ S1 = Hs + (size_t)NNP * 64 + fl * 8;
  float di = act ? dis[w] : 0.f;
  int e0 = 0, e1 = 0;
  if (act) { e0 = rowstart[w]; e1 = rowstart[w + 1]; }   // padded, group-uniform

  float a0[8], a1[8];
  #pragma unroll
  for (int j = 0; j < 8; j++) { a0[j] = 0.f; a1[j] = 0.f; }

  int idxCur = (e0 < e1) ? csr_src[e0 + fl] : 0;
  for (int e = e0; e < e1; e += 8) {
    int cur = idxCur;
    if (e + 8 < e1) idxCur = csr_src[e + 8 + fl];
    int s0 = __shfl(cur, base + 0), s1 = __shfl(cur, base + 1);
    int s2 = __shfl(cur, base + 2), s3 = __shfl(cur, base + 3);
    int s4 = __shfl(cur, base + 4), s5 = __shfl(cur, base + 5);
    int s6 = __shfl(cur, base + 6), s7 = __shfl(cur, base + 7);
    uint4 g0 = *(const uint4*)(S0 + (size_t)s0 * 64);
    uint4 g1 = *(const uint4*)(S0 + (size_t)s1 * 64);
    uint4 g2 = *(const uint4*)(S0 + (size_t)s2 * 64);
    uint4 g3 = *(const uint4*)(S0 + (size_t)s3 * 64);
    uint4 g4 = *(const uint4*)(S0 + (size_t)s4 * 64);
    uint4 g5 = *(const uint4*)(S0 + (size_t)s5 * 64);
    uint4 g6 = *(const uint4*)(S0 + (size_t)s6 * 64);
    uint4 g7 = *(const uint4*)(S0 + (size_t)s7 * 64);
    uint4 h0 = *(const uint4*)(S1 + (size_t)s0 * 64);
    uint4 h1 = *(const uint4*)(S1 + (size_t)s1 * 64);
    uint4 h2 = *(const uint4*)(S1 + (size_t)s2 * 64);
    uint4 h3 = *(const uint4*)(S1 + (size_t)s3 * 64);
    uint4 h4 = *(const uint4*)(S1 + (size_t)s4 * 64);
    uint4 h5 = *(const uint4*)(S1 + (size_t)s5 * 64);
    uint4 h6 = *(const uint4*)(S1 + (size_t)s6 * 64);
    uint4 h7 = *(const uint4*)(S1 + (size_t)s7 * 64);
    a0[0] += ((bflo(g0.x) + bflo(g1.x)) + (bflo(g2.x) + bflo(g3.x))) + ((bflo(g4.x) + bflo(g5.x)) + (bflo(g6.x) + bflo(g7.x)));
    a0[1] += ((bfhi(g0.x) + bfhi(g1.x)) + (bfhi(g2.x) + bfhi(g3.x))) + ((bfhi(g4.x) + bfhi(g5.x)) + (bfhi(g6.x) + bfhi(g7.x)));
    a0[2] += ((bflo(g0.y) + bflo(g1.y)) + (bflo(g2.y) + bflo(g3.y))) + ((bflo(g4.y) + bflo(g5.y)) + (bflo(g6.y) + bflo(g7.y)));
    a0[3] += ((bfhi(g0.y) + bfhi(g1.y)) + (bfhi(g2.y) + bfhi(g3.y))) + ((bfhi(g4.y) + bfhi(g5.y)) + (bfhi(g6.y) + bfhi(g7.y)));
    a0[4] += ((bflo(g0.z) + bflo(g1.z)) + (bflo(g2.z) + bflo(g3.z))) + ((bflo(g4.z) + bflo(g5.z)) + (bflo(g6.z) + bflo(g7.z)));
    a0[5] += ((bfhi(g0.z) + bfhi(g1.z)) + (bfhi(g2.z) + bfhi(g3.z))) + ((bfhi(g4.z) + bfhi(g5.z)) + (bfhi(g6.z) + bfhi(g7.z)));
    a0[6] += ((bflo(g0.w) + bflo(g1.w)) + (bflo(g2.w) + bflo(g3.w))) + ((bflo(g4.w) + bflo(g5.w)) + (bflo(g6.w) + bflo(g7.w)));
    a0[7] += ((bfhi(g0.w) + bfhi(g1.w)) + (bfhi(g2.w) + bfhi(g3.w))) + ((bfhi(g4.w) + bfhi(g5.w)) + (bfhi(g6.w) + bfhi(g7.w)));
    a1[0] += ((bflo(h0.x) + bflo(h1.x)) + (bflo(h2.x) + bflo(h3.x))) + ((bflo(h4.x) + bflo(h5.x)) + (bflo(h6.x) + bflo(h7.x)));
    a1[1] += ((bfhi(h0.x) + bfhi(h1.x)) + (bfhi(h2.x) + bfhi(h3.x))) + ((bfhi(h4.x) + bfhi(h5.x)) + (bfhi(h6.x) + bfhi(h7.x)));
    a1[2] += ((bflo(h0.y) + bflo(h1.y)) + (bflo(h2.y) + bflo(h3.y))) + ((bflo(h4.y) + bflo(h5.y)) + (bflo(h6.y) + bflo(h7.y)));
    a1[3] += ((bfhi(h0.y) + bfhi(h1.y)) + (bfhi(h2.y) + bfhi(h3.y))) + ((bfhi(h4.y) + bfhi(h5.y)) + (bfhi(h6.y) + bfhi(h7.y)));
    a1[4] += ((bflo(h0.z) + bflo(h1.z)) + (bflo(h2.z) + bflo(h3.z))) + ((bflo(h4.z) + bflo(h5.z)) + (bflo(h6.z) + bflo(h7.z)));
    a1[5] += ((bfhi(h0.z) + bfhi(h1.z)) + (bfhi(h2.z) + bfhi(h3.z))) + ((bfhi(h4.z) + bfhi(h5.z)) + (bfhi(h6.z) + bfhi(h7.z)));
    a1[6] += ((bflo(h0.w) + bflo(h1.w)) + (bflo(h2.w) + bflo(h3.w))) + ((bflo(h4.w) + bflo(h5.w)) + (bflo(h6.w) + bflo(h7.w)));
    a1[7] += ((bfhi(h0.w) + bfhi(h1.w)) + (bfhi(h2.w) + bfhi(h3.w))) + ((bfhi(h4.w) + bfhi(h5.w)) + (bfhi(h6.w) + bfhi(h7.w)));
  }

  float rv0[8], rv1[8];
  if (act) {
    uint4 sv0 = *(const uint4*)(S0 + (size_t)w * 64);
    uint4 sv1 = *(const uint4*)(S1 + (size_t)w * 64);
    float se0[8] = { bflo(sv0.x), bfhi(sv0.x), bflo(sv0.y), bfhi(sv0.y),
                     bflo(sv0.z), bfhi(sv0.z), bflo(sv0.w), bfhi(sv0.w) };
    float se1[8] = { bflo(sv1.x), bfhi(sv1.x), bflo(sv1.y), bfhi(sv1.y),
                     bflo(sv1.z), bfhi(sv1.z), bflo(sv1.w), bfhi(sv1.w) };
    #pragma unroll
    for (int j = 0; j < 8; j++) {
      rv0[j] = (a0[j] + se0[j]) * di + bias[fl * 8 + j];
      rv1[j] = (a1[j] + se1[j]) * di + bias[64 + fl * 8 + j];
    }
    uint4 u0, u1;
    u0.x = pack2bf(rv0[0], rv0[1]); u0.y = pack2bf(rv0[2], rv0[3]);
    u0.z = pack2bf(rv0[4], rv0[5]); u0.w = pack2bf(rv0[6], rv0[7]);
    u1.x = pack2bf(rv1[0], rv1[1]); u1.y = pack2bf(rv1[2], rv1[3]);
    u1.z = pack2bf(rv1[4], rv1[5]); u1.w = pack2bf(rv1[6], rv1[7]);
    *(uint4*)(out16 + (size_t)w * 128 + fl * 8)      = u0;
    *(uint4*)(out16 + (size_t)w * 128 + 64 + fl * 8) = u1;
  } else {
    #pragma unroll
    for (int j = 0; j < 8; j++) { rv0[j] = 0.f; rv1[j] = 0.f; }
  }

  // fused BN stats: reduce over node_sub (lane bits 3..5), then cross-wave via LDS
  float q0[8], q1[8];
  #pragma unroll
  for (int j = 0; j < 8; j++) { q0[j] = rv0[j] * rv0[j]; q1[j] = rv1[j] * rv1[j]; }
  #pragma unroll
  for (int off = 8; off <= 32; off <<= 1) {
    #pragma unroll
    for (int j = 0; j < 8; j++) {
      rv0[j] += __shfl_xor(rv0[j], off);
      q0[j]  += __shfl_xor(q0[j], off);
      rv1[j] += __shfl_xor(rv1[j], off);
      q1[j]  += __shfl_xor(q1[j], off);
    }
  }
  if (node_sub == 0) {
    #pragma unroll
    for (int j = 0; j < 8; j++) {
      smS[wv][fl * 8 + j] = rv0[j];      smQ[wv][fl * 8 + j] = q0[j];
      smS[wv][64 + fl * 8 + j] = rv1[j]; smQ[wv][64 + fl * 8 + j] = q1[j];
    }
  }
  __syncthreads();
  if (tid < 128) {
    float s = (smS[0][tid] + smS[1][tid]) + (smS[2][tid] + smS[3][tid]);
    float q = (smQ[0][tid] + smQ[1][tid]) + (smQ[2][tid] + smQ[3][tid]);
    int rep = blockIdx.x & 7;
    atomicAdd(&gstat[rep * 256 + tid], s);
    atomicAdd(&gstat[rep * 256 + 128 + tid], q);
  }
}

// ---------------- final layer: aggregation + fused log_softmax (fp32, R5-proven) ----------------

__global__ __launch_bounds__(256) void k_agg32lsm(const float* __restrict__ H2,
                                                  const float* __restrict__ dis,
                                                  const int* __restrict__ rowstart,
                                                  const int* __restrict__ csr_src,
                                                  const float* __restrict__ bias,
                                                  float* __restrict__ out) {
  int wave = (blockIdx.x * 256 + threadIdx.x) >> 6;
  int lane = threadIdx.x & 63;
  int half = lane >> 5;
  int l = lane & 31;
  int hbase = half * 32;
  int w = wave * 2 + half;
  if (w >= NN) return;   // NN even: both halves exit together
  const float* __restrict__ S = H2 + l;
  float di = dis[w];
  int e0 = rowstart[w], e1 = rowstart[w + 1];
  float acc = 0.f;
  for (int e = e0; e < e1; e += 8) {
    int myIdx = csr_src[e + (l & 7)];
    int s0 = __shfl(myIdx, hbase + 0), s1 = __shfl(myIdx, hbase + 1);
    int s2 = __shfl(myIdx, hbase + 2), s3 = __shfl(myIdx, hbase + 3);
    int s4 = __shfl(myIdx, hbase + 4), s5 = __shfl(myIdx, hbase + 5);
    int s6 = __shfl(myIdx, hbase + 6), s7 = __shfl(myIdx, hbase + 7);
    float h0 = S[(size_t)s0 * 32], h1 = S[(size_t)s1 * 32];
    float h2v = S[(size_t)s2 * 32], h3 = S[(size_t)s3 * 32];
    float h4 = S[(size_t)s4 * 32], h5 = S[(size_t)s5 * 32];
    float h6 = S[(size_t)s6 * 32], h7 = S[(size_t)s7 * 32];
    acc += ((h0 + h1) + (h2v + h3)) + ((h4 + h5) + (h6 + h7));
  }
  float v = (acc + S[(size_t)w * 32]) * di + bias[l];
  float m = v;
  #pragma unroll
  for (int off = 16; off >= 1; off >>= 1) m = fmaxf(m, __shfl_xor(m, off));
  float ex = expf(v - m);
  float s = ex;
  #pragma unroll
  for (int off = 16; off >= 1; off >>= 1) s += __shfl_xor(s, off);
  out[(size_t)w * 32 + l] = v - m - logf(s);
}

// ---------------- launch ----------------

extern "C" void kernel_launch(void* const* d_in, const int* in_sizes, int n_in,
                              void* d_out, int out_size, void* d_ws, size_t ws_size,
                              hipStream_t stream) {
  const float* x   = (const float*)d_in[0];
  const int*   ei  = (const int*)d_in[1];
  const float* W0  = (const float*)d_in[2];
  const float* b0  = (const float*)d_in[3];
  const float* g0  = (const float*)d_in[4];
  const float* be0 = (const float*)d_in[5];
  const float* W1  = (const float*)d_in[6];
  const float* b1  = (const float*)d_in[7];
  const float* g1  = (const float*)d_in[8];
  const float* be1 = (const float*)d_in[9];
  const float* W2  = (const float*)d_in[10];
  const float* b2  = (const float*)d_in[11];
  float* out = (float*)d_out;
  const int* srcI = ei;
  const int* dstI = ei + NE;

  char* p = (char*)d_ws;
  auto take = [&](size_t bytes) { char* r = p; p += (bytes + 255) & ~(size_t)255; return (void*)r; };
  int*   deg8     = (int*)take((size_t)8 * NN * 4);
  int*   cursor   = (int*)take(NN * 4);
  int*   degtot   = (int*)take(NN * 4);
  int*   rowstart = (int*)take((NN + 1) * 4);
  int*   blksum   = (int*)take(64 * 4);
  int*   blkoff   = (int*)take(64 * 4);
  int*   binCnt   = (int*)take(8 * 4);
  float* dis      = (float*)take(NN * 4);
  int*   csr      = (int*)take((size_t)NEP * 4);
  int2*  bin      = (int2*)take((size_t)NBKT * BCAP * 8);
  float* gstat    = (float*)take(4096 * 4);  // 2 layers x 8 reps x 256
  unsigned short* wt16 = (unsigned short*)take((2 * 16384 + 4096) * 2);  // W0^T, W1^T, W2^T bf16
  unsigned short* hs16 = (unsigned short*)take((size_t)NNP * 128 * 2);   // bf16, 2-slice-major
  unsigned short* o16  = (unsigned short*)take((size_t)NN * 128 * 2);    // agg output, packed bf16
  unsigned short* xA16 = (unsigned short*)take((size_t)NN * 128 * 2);    // layer-1 input, packed bf16
  float* h2       = (float*)take((size_t)NNP * 32 * 4);

  k_init<<<(NEP + 255) / 256, 256, 0, stream>>>(deg8, gstat, csr, binCnt, W0, W1, W2, wt16);
  k_binA<<<(NE + 1023) / 1024, 1024, 0, stream>>>(srcI, dstI, deg8, binCnt, bin);
  k_scan1<<<NBLK, 1024, 0, stream>>>(deg8, degtot, rowstart, blksum);
  k_scan2<<<1, 64, 0, stream>>>(blksum, blkoff, rowstart);
  k_scan3<<<(NN + 255) / 256, 256, 0, stream>>>(rowstart, blkoff, degtot, cursor, dis, hs16, h2);
  k_fillB<<<512, 256, 0, stream>>>(bin, binCnt, cursor, csr);

  const int aggGrid = (NN + 31) / 32;   // 8 nodes/wave, both slices, 4 waves/block
  const int aggGrid32 = (NN + 7) / 8;   // 2 nodes/wave

  // ---- layer 0 ----
  k_gemm128<<<(NN + 63) / 64, 256, 0, stream>>>(x, wt16, dis, hs16, NN);
  k_agg128s<<<aggGrid, 256, 0, stream>>>(hs16, dis, rowstart, csr, b0, o16, gstat);

  // ---- layer 1 (BN finalize + BN/ReLU/residual fused into GEMM stage-A) ----
  k_gemm128f<<<(NN + 63) / 64, 256, 0, stream>>>(o16, x, xA16, gstat, g0, be0,
                                                 wt16 + 16384, dis, hs16, NN);
  k_agg128s<<<aggGrid, 256, 0, stream>>>(hs16, dis, rowstart, csr, b1, o16, gstat + 2048);

  // ---- final conv (BN finalize + fuse in-kernel, xB never materialized) ----
  k_gemm32mf<<<(NN + 63) / 64, 256, 0, stream>>>(o16, xA16, gstat + 2048, g1, be1,
                                                 wt16 + 32768, dis, h2, NN);
  k_agg32lsm<<<aggGrid32, 256, 0, stream>>>(h2, dis, rowstart, csr, b2, out);
}